// Round 4
// baseline (387.252 us; speedup 1.0000x reference)
//
#include <hip/hip_runtime.h>

#define TS 524288u          // 2^19
#define PRIME 2654435761u
#define NPTS 1048576u
#define MASK (TS - 1u)
#define NB 4096u            // 64x64 spatial buckets

typedef float vfloat4 __attribute__((ext_vector_type(4)));

// floor(16 * fl32(g)^l), g = 64^(1/15); fl32(g) rounds UP so the exact-integer
// levels (5,10,15) floor to 64/256/1024 under correctly-rounded powf (= numpy).
__device__ __constant__ float c_scale[16] = {
    16.f, 21.f, 27.f, 36.f, 48.f, 64.f, 84.f, 111.f,
    147.f, 194.f, 256.f, 337.f, 445.f, 588.f, 776.f, 1024.f
};

// Staged levels 0-3 (res 16,21,27,36 -> grid widths 17,22,28,37).
#define W0 17
#define W1 22
#define W2 28
#define W3 37
#define B0 0
#define B1 (B0 + W0*W0)        // 289
#define B2 (B1 + W1*W1)        // 773
#define B3 (B2 + W2*W2)        // 1557
#define NSTAGE (B3 + W3*W3)    // 2926 float2 = 23408 B

__device__ __forceinline__ unsigned bucket_of(float2 xy) {
    unsigned bx = (unsigned)(xy.x * 64.0f); if (bx > 63u) bx = 63u;
    unsigned by = (unsigned)(xy.y * 64.0f); if (by > 63u) by = 63u;
    return by * 64u + bx;
}

// ---- Pass 1: per-bucket histogram (direct global atomics; 4096 counters
// spread over 256 L2 lines -> ample atomic parallelism) ----
__global__ __launch_bounds__(256) void hist_kernel(
    const float2* __restrict__ x, unsigned* __restrict__ cnt)
{
    unsigned stride = gridDim.x * 256u;
    for (unsigned p = blockIdx.x * 256u + threadIdx.x; p < NPTS; p += stride)
        atomicAdd(&cnt[bucket_of(x[p])], 1u);
}

// ---- Pass 2: exclusive scan of 4096 counters, in place (single block) ----
__global__ __launch_bounds__(256) void scan_kernel(unsigned* __restrict__ cnt)
{
    __shared__ unsigned partial[256];
    unsigned t = threadIdx.x;
    unsigned v[16], s = 0;
#pragma unroll
    for (int i = 0; i < 16; ++i) { v[i] = cnt[t * 16u + i]; s += v[i]; }
    partial[t] = s;
    __syncthreads();
    for (unsigned d = 1; d < 256u; d <<= 1) {
        unsigned val = (t >= d) ? partial[t - d] : 0u;
        __syncthreads();
        partial[t] += val;
        __syncthreads();
    }
    unsigned run = (t > 0) ? partial[t - 1] : 0u;
#pragma unroll
    for (int i = 0; i < 16; ++i) { unsigned c = v[i]; cnt[t * 16u + i] = run; run += c; }
}

// ---- Pass 3: scatter points into bucket-sorted order (cnt = cursors) ----
__global__ __launch_bounds__(256) void scatter_kernel(
    const float2* __restrict__ x, unsigned* __restrict__ cnt,
    vfloat4* __restrict__ pts)
{
    unsigned stride = gridDim.x * 256u;
    for (unsigned p = blockIdx.x * 256u + threadIdx.x; p < NPTS; p += stride) {
        float2 xy = x[p];
        unsigned pos = atomicAdd(&cnt[bucket_of(xy)], 1u);
        vfloat4 r;
        r.x = xy.x; r.y = xy.y; r.z = __uint_as_float(p); r.w = 0.0f;
        pts[pos] = r;
    }
}

// ---- Pass 4: main encode over spatially-sorted points (round-0 structure) ----
__global__ __launch_bounds__(256) void hashenc_sorted(
    const vfloat4* __restrict__ pts,
    const float2* __restrict__ tab,
    vfloat4* __restrict__ out,
    unsigned pts_per_block)
{
    __shared__ float2 lds[NSTAGE];
    unsigned tid = threadIdx.x;

#define STAGE(L, W, B)                                                  \
    for (unsigned i = tid; i < (unsigned)((W)*(W)); i += 256u) {        \
        unsigned vy = i / (unsigned)(W), vx = i % (unsigned)(W);        \
        unsigned h = ((vx ^ (vy * PRIME)) & MASK) | ((unsigned)(L) << 19); \
        lds[(B) + i] = tab[h];                                          \
    }
    STAGE(0, W0, B0)
    STAGE(1, W1, B1)
    STAGE(2, W2, B2)
    STAGE(3, W3, B3)
#undef STAGE
    __syncthreads();

    const unsigned lq = tid & 3u;          // level quad: levels 4lq..4lq+3
    const unsigned lane_p = tid >> 2;      // 0..63: point slot within iteration
    const unsigned l0 = lq << 2;
    const unsigned bs = blockIdx.x * pts_per_block;
    unsigned be = bs + pts_per_block;
    if (be > NPTS) be = NPTS;

    const unsigned Wk[4] = { W0, W1, W2, W3 };
    const unsigned Bk[4] = { B0, B1, B2, B3 };

    for (unsigned p = bs + lane_p; p < be; p += 64u) {
        vfloat4 rec = pts[p];
        float2 xy; xy.x = rec.x; xy.y = rec.y;
        unsigned idx = __float_as_uint(rec.z);
        vfloat4 r[2];

        if (lq == 0u) {
#pragma unroll
            for (int k = 0; k < 4; ++k) {
                float s = c_scale[k];
                float sx = xy.x * s, sy = xy.y * s;
                float fxf = floorf(sx), fyf = floorf(sy);
                float cxf = ceilf(sx),  cyf = ceilf(sy);
                float ox = sx - fxf, oy = sy - fyf;
                unsigned fx = (unsigned)(int)fxf, fy = (unsigned)(int)fyf;
                unsigned cx = (unsigned)(int)cxf, cy = (unsigned)(int)cyf;
                unsigned w = Wk[k], b = Bk[k];
                float2 f0 = lds[b + cy * w + cx];
                float2 f1 = lds[b + fy * w + cx];
                float2 f2 = lds[b + cy * w + fx];
                float2 f3 = lds[b + fy * w + fx];
                float wox = 1.0f - ox, woy = 1.0f - oy;
                float f03x = f0.x * ox + f3.x * wox;
                float f03y = f0.y * ox + f3.y * wox;
                float f12x = f1.x * ox + f2.x * wox;
                float f12y = f1.y * ox + f2.y * wox;
                float ex = f03x * oy + f12x * woy;
                float ey = f03y * oy + f12y * woy;
                if ((k & 1) == 0) { r[k >> 1].x = ex; r[k >> 1].y = ey; }
                else              { r[k >> 1].z = ex; r[k >> 1].w = ey; }
            }
        } else {
#pragma unroll
            for (int k = 0; k < 4; ++k) {
                unsigned l = l0 + (unsigned)k;
                float s = c_scale[l];
                float sx = xy.x * s, sy = xy.y * s;
                float fxf = floorf(sx), fyf = floorf(sy);
                float cxf = ceilf(sx),  cyf = ceilf(sy);
                float ox = sx - fxf, oy = sy - fyf;
                unsigned fx = (unsigned)(int)fxf, fy = (unsigned)(int)fyf;
                unsigned cx = (unsigned)(int)cxf, cy = (unsigned)(int)cyf;
                unsigned hcy = cy * PRIME, hfy = fy * PRIME;
                unsigned base = l << 19;
                float2 f0 = tab[((cx ^ hcy) & MASK) | base];
                float2 f1 = tab[((cx ^ hfy) & MASK) | base];
                float2 f2 = tab[((fx ^ hcy) & MASK) | base];
                float2 f3 = tab[((fx ^ hfy) & MASK) | base];
                float wox = 1.0f - ox, woy = 1.0f - oy;
                float f03x = f0.x * ox + f3.x * wox;
                float f03y = f0.y * ox + f3.y * wox;
                float f12x = f1.x * ox + f2.x * wox;
                float f12y = f1.y * ox + f2.y * wox;
                float ex = f03x * oy + f12x * woy;
                float ey = f03y * oy + f12y * woy;
                if ((k & 1) == 0) { r[k >> 1].x = ex; r[k >> 1].y = ey; }
                else              { r[k >> 1].z = ex; r[k >> 1].w = ey; }
            }
        }

        // Output goes to the ORIGINAL point index; the 4 lq-threads of one
        // point cover idx*8 .. idx*8+7 -> one contiguous 128B record (2 full
        // lines), merged in L2 before writeout.
        unsigned o = idx * 8u + lq * 2u;
        __builtin_nontemporal_store(r[0], &out[o]);
        __builtin_nontemporal_store(r[1], &out[o + 1]);
    }
}

// ---- Fallback: proven round-0 kernel (unsorted), used if ws too small ----
__global__ __launch_bounds__(256) void hashenc_kernel(
    const float2* __restrict__ x,
    const float2* __restrict__ tab,
    vfloat4* __restrict__ out,
    unsigned pts_per_block)
{
    __shared__ float2 lds[NSTAGE];
    unsigned tid = threadIdx.x;

#define STAGE(L, W, B)                                                  \
    for (unsigned i = tid; i < (unsigned)((W)*(W)); i += 256u) {        \
        unsigned vy = i / (unsigned)(W), vx = i % (unsigned)(W);        \
        unsigned h = ((vx ^ (vy * PRIME)) & MASK) | ((unsigned)(L) << 19); \
        lds[(B) + i] = tab[h];                                          \
    }
    STAGE(0, W0, B0)
    STAGE(1, W1, B1)
    STAGE(2, W2, B2)
    STAGE(3, W3, B3)
#undef STAGE
    __syncthreads();

    const unsigned lq = tid & 3u;
    const unsigned lane_p = tid >> 2;
    const unsigned l0 = lq << 2;
    const unsigned bs = blockIdx.x * pts_per_block;
    unsigned be = bs + pts_per_block;
    if (be > NPTS) be = NPTS;

    const unsigned Wk[4] = { W0, W1, W2, W3 };
    const unsigned Bk[4] = { B0, B1, B2, B3 };

    for (unsigned p = bs + lane_p; p < be; p += 64u) {
        float2 xy = x[p];
        vfloat4 r[2];

        if (lq == 0u) {
#pragma unroll
            for (int k = 0; k < 4; ++k) {
                float s = c_scale[k];
                float sx = xy.x * s, sy = xy.y * s;
                float fxf = floorf(sx), fyf = floorf(sy);
                float cxf = ceilf(sx),  cyf = ceilf(sy);
                float ox = sx - fxf, oy = sy - fyf;
                unsigned fx = (unsigned)(int)fxf, fy = (unsigned)(int)fyf;
                unsigned cx = (unsigned)(int)cxf, cy = (unsigned)(int)cyf;
                unsigned w = Wk[k], b = Bk[k];
                float2 f0 = lds[b + cy * w + cx];
                float2 f1 = lds[b + fy * w + cx];
                float2 f2 = lds[b + cy * w + fx];
                float2 f3 = lds[b + fy * w + fx];
                float wox = 1.0f - ox, woy = 1.0f - oy;
                float f03x = f0.x * ox + f3.x * wox;
                float f03y = f0.y * ox + f3.y * wox;
                float f12x = f1.x * ox + f2.x * wox;
                float f12y = f1.y * ox + f2.y * wox;
                float ex = f03x * oy + f12x * woy;
                float ey = f03y * oy + f12y * woy;
                if ((k & 1) == 0) { r[k >> 1].x = ex; r[k >> 1].y = ey; }
                else              { r[k >> 1].z = ex; r[k >> 1].w = ey; }
            }
        } else {
#pragma unroll
            for (int k = 0; k < 4; ++k) {
                unsigned l = l0 + (unsigned)k;
                float s = c_scale[l];
                float sx = xy.x * s, sy = xy.y * s;
                float fxf = floorf(sx), fyf = floorf(sy);
                float cxf = ceilf(sx),  cyf = ceilf(sy);
                float ox = sx - fxf, oy = sy - fyf;
                unsigned fx = (unsigned)(int)fxf, fy = (unsigned)(int)fyf;
                unsigned cx = (unsigned)(int)cxf, cy = (unsigned)(int)cyf;
                unsigned hcy = cy * PRIME, hfy = fy * PRIME;
                unsigned base = l << 19;
                float2 f0 = tab[((cx ^ hcy) & MASK) | base];
                float2 f1 = tab[((cx ^ hfy) & MASK) | base];
                float2 f2 = tab[((fx ^ hcy) & MASK) | base];
                float2 f3 = tab[((fx ^ hfy) & MASK) | base];
                float wox = 1.0f - ox, woy = 1.0f - oy;
                float f03x = f0.x * ox + f3.x * wox;
                float f03y = f0.y * ox + f3.y * wox;
                float f12x = f1.x * ox + f2.x * wox;
                float f12y = f1.y * ox + f2.y * wox;
                float ex = f03x * oy + f12x * woy;
                float ey = f03y * oy + f12y * woy;
                if ((k & 1) == 0) { r[k >> 1].x = ex; r[k >> 1].y = ey; }
                else              { r[k >> 1].z = ex; r[k >> 1].w = ey; }
            }
        }

        unsigned o = p * 8u + lq * 2u;
        __builtin_nontemporal_store(r[0], &out[o]);
        __builtin_nontemporal_store(r[1], &out[o + 1]);
    }
}

extern "C" void kernel_launch(void* const* d_in, const int* in_sizes, int n_in,
                              void* d_out, int out_size, void* d_ws, size_t ws_size,
                              hipStream_t stream)
{
    const float2* x   = (const float2*)d_in[0];
    const float2* tab = (const float2*)d_in[1];
    vfloat4* out = (vfloat4*)d_out;

    const size_t ws_need = 16384u + (size_t)NPTS * 16u;   // cnt[4096] + pts[1M]

    if (d_ws != nullptr && ws_size >= ws_need) {
        unsigned* cnt = (unsigned*)d_ws;
        vfloat4* pts  = (vfloat4*)((char*)d_ws + 16384u);

        hipMemsetAsync(cnt, 0, NB * sizeof(unsigned), stream);
        hist_kernel<<<2048, 256, 0, stream>>>(x, cnt);
        scan_kernel<<<1, 256, 0, stream>>>(cnt);
        scatter_kernel<<<2048, 256, 0, stream>>>(x, cnt, pts);

        const unsigned n_blocks = 1536u;
        const unsigned ppb = (NPTS + n_blocks - 1u) / n_blocks; // 683
        hashenc_sorted<<<n_blocks, 256, 0, stream>>>(pts, tab, out, ppb);
    } else {
        const unsigned n_blocks = 1536u;
        const unsigned ppb = (NPTS + n_blocks - 1u) / n_blocks;
        hashenc_kernel<<<n_blocks, 256, 0, stream>>>(x, tab, out, ppb);
    }
}

// Round 5
// 295.447 us; speedup vs baseline: 1.3107x; 1.3107x over previous
//
#include <hip/hip_runtime.h>

#define TS 524288u          // 2^19
#define PRIME 2654435761u
#define NPTS 1048576u
#define MASK (TS - 1u)
#define NBUK 4096u          // 64x64 spatial buckets
#define CAP 320u            // bucket capacity: lambda=256, +4 sigma; overflow handled
#define OVF_CAP 8192u

// ---- ws layout (bytes); total 15.86 MB < 16.79 MB proven available ----
#define WS_CURSOR   0u          // u32[4096]          = 16384
#define WS_OVFCNT   16384u      // u32 (padded)
#define WS_OVF_XY   16640u      // float2[8192]       = 65536
#define WS_OVF_IDX  82176u      // u32[8192]          = 32768
#define WS_XYBUF    131072u     // float2[4096*320]   = 10485760
#define WS_IDXBUF   10616832u   // u32[4096*320]      = 5242880
#define WS_NEED     15859712u

typedef float vfloat4 __attribute__((ext_vector_type(4)));

// floor(16 * fl32(g)^l), g = 64^(1/15); fl32(g) rounds UP so the exact-integer
// levels (5,10,15) floor to 64/256/1024 under correctly-rounded powf (= numpy).
__device__ __constant__ float c_scale[16] = {
    16.f, 21.f, 27.f, 36.f, 48.f, 64.f, 84.f, 111.f,
    147.f, 194.f, 256.f, 337.f, 445.f, 588.f, 776.f, 1024.f
};

__device__ __forceinline__ unsigned bucket_of(float2 xy) {
    unsigned bx = (unsigned)(xy.x * 64.0f); if (bx > 63u) bx = 63u;
    unsigned by = (unsigned)(xy.y * 64.0f); if (by > 63u) by = 63u;
    return by * 64u + bx;
}

// Shared bilinear tap: one level, global table.
__device__ __forceinline__ void enc_level(
    float2 xy, unsigned l, const float2* __restrict__ tab,
    float& ex, float& ey)
{
    float s = c_scale[l];
    float sx = xy.x * s, sy = xy.y * s;
    float fxf = floorf(sx), fyf = floorf(sy);
    float cxf = ceilf(sx),  cyf = ceilf(sy);
    float ox = sx - fxf, oy = sy - fyf;
    unsigned fx = (unsigned)(int)fxf, fy = (unsigned)(int)fyf;
    unsigned cx = (unsigned)(int)cxf, cy = (unsigned)(int)cyf;
    unsigned hcy = cy * PRIME, hfy = fy * PRIME;
    unsigned base = l << 19;
    float2 f0 = tab[((cx ^ hcy) & MASK) | base];
    float2 f1 = tab[((cx ^ hfy) & MASK) | base];
    float2 f2 = tab[((fx ^ hcy) & MASK) | base];
    float2 f3 = tab[((fx ^ hfy) & MASK) | base];
    float wox = 1.0f - ox, woy = 1.0f - oy;
    float f03x = f0.x * ox + f3.x * wox;
    float f03y = f0.y * ox + f3.y * wox;
    float f12x = f1.x * ox + f2.x * wox;
    float f12y = f1.y * ox + f2.y * wox;
    ex = f03x * oy + f12x * woy;
    ey = f03y * oy + f12y * woy;
}

// ---- Pass 0: init cursors (cursor[b] = b*CAP) + overflow counter ----
__global__ __launch_bounds__(256) void init_kernel(
    unsigned* __restrict__ cursor, unsigned* __restrict__ ovf_cnt)
{
    unsigned t = blockIdx.x * 256u + threadIdx.x;
    if (t < NBUK) cursor[t] = t * CAP;
    if (t == 0u) *ovf_cnt = 0u;
}

// ---- Pass 1: fused LDS-privatized counting sort into fixed-cap regions ----
// 256 blocks x 4096-point chunks. Global atomics: one per (block, nonempty
// bin) on AGGREGATED counts (~660K total, was 2M single increments).
__global__ __launch_bounds__(256) void sort_kernel(
    const float2* __restrict__ x,
    unsigned* __restrict__ cursor,
    unsigned* __restrict__ ovf_cnt,
    float2* __restrict__ ovf_xy,
    unsigned* __restrict__ ovf_idx,
    float2* __restrict__ xybuf,
    unsigned* __restrict__ idxbuf)
{
    __shared__ unsigned lhist[NBUK];   // counts, then running local offsets
    __shared__ unsigned lbase[NBUK];   // reserved global base
    __shared__ unsigned lcap[NBUK];    // granted capacity (take)
    unsigned tid = threadIdx.x;
    unsigned cbase = blockIdx.x * 4096u;

    for (unsigned j = tid; j < NBUK; j += 256u) lhist[j] = 0u;
    __syncthreads();

    float2 pxy[16];
#pragma unroll
    for (int k = 0; k < 16; ++k) {
        float2 xy = x[cbase + tid + (unsigned)k * 256u];
        pxy[k] = xy;
        atomicAdd(&lhist[bucket_of(xy)], 1u);
    }
    __syncthreads();

    for (unsigned j = tid; j < NBUK; j += 256u) {
        unsigned c = lhist[j];
        unsigned base = 0u, take = 0u;
        if (c) {
            base = atomicAdd(&cursor[j], c);
            unsigned prior = base - j * CAP;
            unsigned avail = (prior >= CAP) ? 0u : (CAP - prior);
            take = (c < avail) ? c : avail;
        }
        lbase[j] = base;
        lcap[j]  = take;
        lhist[j] = 0u;                 // reuse as running local offset
    }
    __syncthreads();

#pragma unroll
    for (int k = 0; k < 16; ++k) {
        float2 xy = pxy[k];
        unsigned b = bucket_of(xy);
        unsigned idx = cbase + tid + (unsigned)k * 256u;
        unsigned loff = atomicAdd(&lhist[b], 1u);
        if (loff < lcap[b]) {
            unsigned pos = lbase[b] + loff;
            xybuf[pos] = xy;
            idxbuf[pos] = idx;
        } else {
            unsigned o = atomicAdd(ovf_cnt, 1u);
            if (o < OVF_CAP) { ovf_xy[o] = xy; ovf_idx[o] = idx; }
        }
    }
}

// ---- Pass 2: encode, one wave per bucket. No LDS (sorted points make all
// 16 levels L1/L2-hot; coarse-level staging is dead weight). ----
__global__ __launch_bounds__(256) void encode_kernel(
    const float2* __restrict__ xybuf,
    const unsigned* __restrict__ idxbuf,
    const unsigned* __restrict__ cursor,
    const float2* __restrict__ tab,
    vfloat4* __restrict__ out)
{
    unsigned tid  = threadIdx.x;
    unsigned wave = tid >> 6;              // 0..3: bucket within block
    unsigned lane = tid & 63u;
    unsigned lq   = lane & 3u;             // level quad: levels 4lq..4lq+3
    unsigned s0   = lane >> 2;             // 0..15: slot within iteration
    unsigned b    = blockIdx.x * 4u + wave;
    unsigned total = cursor[b] - b * CAP;
    unsigned cnt  = (total < CAP) ? total : CAP;
    unsigned l0   = lq << 2;
    unsigned pbase = b * CAP;

    for (unsigned s = s0; s < cnt; s += 16u) {
        float2 xy   = xybuf[pbase + s];
        unsigned idx = idxbuf[pbase + s];
        vfloat4 r[2];
#pragma unroll
        for (int k = 0; k < 4; ++k) {
            float ex, ey;
            enc_level(xy, l0 + (unsigned)k, tab, ex, ey);
            if ((k & 1) == 0) { r[k >> 1].x = ex; r[k >> 1].y = ey; }
            else              { r[k >> 1].z = ex; r[k >> 1].w = ey; }
        }
        // 4 lq-threads of one point cover idx*8..idx*8+7: one aligned,
        // fully-written 128B record (2 lines) -> no write amplification.
        unsigned o = idx * 8u + lq * 2u;
        __builtin_nontemporal_store(r[0], &out[o]);
        __builtin_nontemporal_store(r[1], &out[o + 1]);
    }
}

// ---- Pass 3: encode overflow points directly (expected ~0-100 points) ----
__global__ __launch_bounds__(256) void fixup_kernel(
    const unsigned* __restrict__ ovf_cnt,
    const float2* __restrict__ ovf_xy,
    const unsigned* __restrict__ ovf_idx,
    const float2* __restrict__ tab,
    vfloat4* __restrict__ out)
{
    unsigned n = *ovf_cnt; if (n > OVF_CAP) n = OVF_CAP;
    unsigned stride = gridDim.x * 256u;
    for (unsigned p = blockIdx.x * 256u + threadIdx.x; p < n; p += stride) {
        float2 xy = ovf_xy[p];
        unsigned idx = ovf_idx[p];
        vfloat4 acc[8];
#pragma unroll
        for (int l = 0; l < 16; ++l) {
            float ex, ey;
            enc_level(xy, (unsigned)l, tab, ex, ey);
            if ((l & 1) == 0) { acc[l >> 1].x = ex; acc[l >> 1].y = ey; }
            else              { acc[l >> 1].z = ex; acc[l >> 1].w = ey; }
        }
#pragma unroll
        for (int q = 0; q < 8; ++q) out[idx * 8u + (unsigned)q] = acc[q];
    }
}

// ---- Fallback: proven round-0 unsorted kernel (ws too small; never expected) ----
#define W0 17
#define W1 22
#define W2 28
#define W3 37
#define B0 0
#define B1 (B0 + W0*W0)
#define B2 (B1 + W1*W1)
#define B3 (B2 + W2*W2)
#define NSTAGE (B3 + W3*W3)

__global__ __launch_bounds__(256) void hashenc_kernel(
    const float2* __restrict__ x,
    const float2* __restrict__ tab,
    vfloat4* __restrict__ out,
    unsigned pts_per_block)
{
    __shared__ float2 lds[NSTAGE];
    unsigned tid = threadIdx.x;

#define STAGE(L, W, B)                                                  \
    for (unsigned i = tid; i < (unsigned)((W)*(W)); i += 256u) {        \
        unsigned vy = i / (unsigned)(W), vx = i % (unsigned)(W);        \
        unsigned h = ((vx ^ (vy * PRIME)) & MASK) | ((unsigned)(L) << 19); \
        lds[(B) + i] = tab[h];                                          \
    }
    STAGE(0, W0, B0)
    STAGE(1, W1, B1)
    STAGE(2, W2, B2)
    STAGE(3, W3, B3)
#undef STAGE
    __syncthreads();

    const unsigned lq = tid & 3u;
    const unsigned lane_p = tid >> 2;
    const unsigned l0 = lq << 2;
    const unsigned bs = blockIdx.x * pts_per_block;
    unsigned be = bs + pts_per_block;
    if (be > NPTS) be = NPTS;

    const unsigned Wk[4] = { W0, W1, W2, W3 };
    const unsigned Bk[4] = { B0, B1, B2, B3 };

    for (unsigned p = bs + lane_p; p < be; p += 64u) {
        float2 xy = x[p];
        vfloat4 r[2];

        if (lq == 0u) {
#pragma unroll
            for (int k = 0; k < 4; ++k) {
                float s = c_scale[k];
                float sx = xy.x * s, sy = xy.y * s;
                float fxf = floorf(sx), fyf = floorf(sy);
                float cxf = ceilf(sx),  cyf = ceilf(sy);
                float ox = sx - fxf, oy = sy - fyf;
                unsigned fx = (unsigned)(int)fxf, fy = (unsigned)(int)fyf;
                unsigned cx = (unsigned)(int)cxf, cy = (unsigned)(int)cyf;
                unsigned w = Wk[k], b = Bk[k];
                float2 f0 = lds[b + cy * w + cx];
                float2 f1 = lds[b + fy * w + cx];
                float2 f2 = lds[b + cy * w + fx];
                float2 f3 = lds[b + fy * w + fx];
                float wox = 1.0f - ox, woy = 1.0f - oy;
                float f03x = f0.x * ox + f3.x * wox;
                float f03y = f0.y * ox + f3.y * wox;
                float f12x = f1.x * ox + f2.x * wox;
                float f12y = f1.y * ox + f2.y * wox;
                float ex = f03x * oy + f12x * woy;
                float ey = f03y * oy + f12y * woy;
                if ((k & 1) == 0) { r[k >> 1].x = ex; r[k >> 1].y = ey; }
                else              { r[k >> 1].z = ex; r[k >> 1].w = ey; }
            }
        } else {
#pragma unroll
            for (int k = 0; k < 4; ++k) {
                float ex, ey;
                enc_level(xy, l0 + (unsigned)k, tab, ex, ey);
                if ((k & 1) == 0) { r[k >> 1].x = ex; r[k >> 1].y = ey; }
                else              { r[k >> 1].z = ex; r[k >> 1].w = ey; }
            }
        }

        unsigned o = p * 8u + lq * 2u;
        __builtin_nontemporal_store(r[0], &out[o]);
        __builtin_nontemporal_store(r[1], &out[o + 1]);
    }
}

extern "C" void kernel_launch(void* const* d_in, const int* in_sizes, int n_in,
                              void* d_out, int out_size, void* d_ws, size_t ws_size,
                              hipStream_t stream)
{
    const float2* x   = (const float2*)d_in[0];
    const float2* tab = (const float2*)d_in[1];
    vfloat4* out = (vfloat4*)d_out;

    if (d_ws != nullptr && ws_size >= (size_t)WS_NEED) {
        char* ws = (char*)d_ws;
        unsigned* cursor  = (unsigned*)(ws + WS_CURSOR);
        unsigned* ovf_cnt = (unsigned*)(ws + WS_OVFCNT);
        float2*   ovf_xy  = (float2*)  (ws + WS_OVF_XY);
        unsigned* ovf_idx = (unsigned*)(ws + WS_OVF_IDX);
        float2*   xybuf   = (float2*)  (ws + WS_XYBUF);
        unsigned* idxbuf  = (unsigned*)(ws + WS_IDXBUF);

        init_kernel<<<16, 256, 0, stream>>>(cursor, ovf_cnt);
        sort_kernel<<<256, 256, 0, stream>>>(x, cursor, ovf_cnt, ovf_xy,
                                             ovf_idx, xybuf, idxbuf);
        encode_kernel<<<NBUK / 4, 256, 0, stream>>>(xybuf, idxbuf, cursor, tab, out);
        fixup_kernel<<<8, 256, 0, stream>>>(ovf_cnt, ovf_xy, ovf_idx, tab, out);
    } else {
        const unsigned n_blocks = 1536u;
        const unsigned ppb = (NPTS + n_blocks - 1u) / n_blocks;
        hashenc_kernel<<<n_blocks, 256, 0, stream>>>(x, tab, out, ppb);
    }
}

// Round 6
// 281.689 us; speedup vs baseline: 1.3748x; 1.0488x over previous
//
#include <hip/hip_runtime.h>

#define TS 524288u          // 2^19
#define PRIME 2654435761u
#define NPTS 1048576u
#define MASK (TS - 1u)
#define NBUK 4096u          // 64x64 spatial buckets
#define CAP 320u            // bucket capacity: lambda=256, +4 sigma; overflow handled
#define OVF_CAP 8192u

// ---- ws layout (bytes); total 15.86 MB < 16.79 MB proven available ----
#define WS_CURSOR   0u          // u32[4096]          = 16384
#define WS_OVFCNT   16384u      // u32 (padded)
#define WS_OVF_XY   16640u      // float2[8192]       = 65536
#define WS_OVF_IDX  82176u      // u32[8192]          = 32768
#define WS_XYBUF    131072u     // float2[4096*320]   = 10485760
#define WS_IDXBUF   10616832u   // u32[4096*320]      = 5242880
#define WS_NEED     15859712u

typedef float vfloat4 __attribute__((ext_vector_type(4)));

// floor(16 * fl32(g)^l), g = 64^(1/15); fl32(g) rounds UP so the exact-integer
// levels (5,10,15) floor to 64/256/1024 under correctly-rounded powf (= numpy).
__device__ __constant__ float c_scale[16] = {
    16.f, 21.f, 27.f, 36.f, 48.f, 64.f, 84.f, 111.f,
    147.f, 194.f, 256.f, 337.f, 445.f, 588.f, 776.f, 1024.f
};

// Staged levels 0-3 (res 16,21,27,36 -> grid widths 17,22,28,37).
#define W0 17
#define W1 22
#define W2 28
#define W3 37
#define B0 0
#define B1 (B0 + W0*W0)        // 289
#define B2 (B1 + W1*W1)        // 773
#define B3 (B2 + W2*W2)        // 1557
#define NSTAGE (B3 + W3*W3)    // 2926 float2 = 23408 B

__device__ __forceinline__ unsigned bucket_of(float2 xy) {
    unsigned bx = (unsigned)(xy.x * 64.0f); if (bx > 63u) bx = 63u;
    unsigned by = (unsigned)(xy.y * 64.0f); if (by > 63u) by = 63u;
    return by * 64u + bx;
}

// Shared bilinear tap: one level, global table.
__device__ __forceinline__ void enc_level(
    float2 xy, unsigned l, const float2* __restrict__ tab,
    float& ex, float& ey)
{
    float s = c_scale[l];
    float sx = xy.x * s, sy = xy.y * s;
    float fxf = floorf(sx), fyf = floorf(sy);
    float cxf = ceilf(sx),  cyf = ceilf(sy);
    float ox = sx - fxf, oy = sy - fyf;
    unsigned fx = (unsigned)(int)fxf, fy = (unsigned)(int)fyf;
    unsigned cx = (unsigned)(int)cxf, cy = (unsigned)(int)cyf;
    unsigned hcy = cy * PRIME, hfy = fy * PRIME;
    unsigned base = l << 19;
    float2 f0 = tab[((cx ^ hcy) & MASK) | base];
    float2 f1 = tab[((cx ^ hfy) & MASK) | base];
    float2 f2 = tab[((fx ^ hcy) & MASK) | base];
    float2 f3 = tab[((fx ^ hfy) & MASK) | base];
    float wox = 1.0f - ox, woy = 1.0f - oy;
    float f03x = f0.x * ox + f3.x * wox;
    float f03y = f0.y * ox + f3.y * wox;
    float f12x = f1.x * ox + f2.x * wox;
    float f12y = f1.y * ox + f2.y * wox;
    ex = f03x * oy + f12x * woy;
    ey = f03y * oy + f12y * woy;
}

// ---- Pass 0: init cursors (cursor[b] = b*CAP) + overflow counter ----
__global__ __launch_bounds__(256) void init_kernel(
    unsigned* __restrict__ cursor, unsigned* __restrict__ ovf_cnt)
{
    unsigned t = blockIdx.x * 256u + threadIdx.x;
    if (t < NBUK) cursor[t] = t * CAP;
    if (t == 0u) *ovf_cnt = 0u;
}

// ---- Pass 1: fused LDS-privatized counting sort into fixed-cap regions ----
// 256 blocks x 4096-point chunks. Global atomics: one per (block, nonempty
// bin) on AGGREGATED counts (~660K total). Measured ~40us.
__global__ __launch_bounds__(256) void sort_kernel(
    const float2* __restrict__ x,
    unsigned* __restrict__ cursor,
    unsigned* __restrict__ ovf_cnt,
    float2* __restrict__ ovf_xy,
    unsigned* __restrict__ ovf_idx,
    float2* __restrict__ xybuf,
    unsigned* __restrict__ idxbuf)
{
    __shared__ unsigned lhist[NBUK];   // counts, then running local offsets
    __shared__ unsigned lbase[NBUK];   // reserved global base
    __shared__ unsigned lcap[NBUK];    // granted capacity (take)
    unsigned tid = threadIdx.x;
    unsigned cbase = blockIdx.x * 4096u;

    for (unsigned j = tid; j < NBUK; j += 256u) lhist[j] = 0u;
    __syncthreads();

    float2 pxy[16];
#pragma unroll
    for (int k = 0; k < 16; ++k) {
        float2 xy = x[cbase + tid + (unsigned)k * 256u];
        pxy[k] = xy;
        atomicAdd(&lhist[bucket_of(xy)], 1u);
    }
    __syncthreads();

    for (unsigned j = tid; j < NBUK; j += 256u) {
        unsigned c = lhist[j];
        unsigned base = 0u, take = 0u;
        if (c) {
            base = atomicAdd(&cursor[j], c);
            unsigned prior = base - j * CAP;
            unsigned avail = (prior >= CAP) ? 0u : (CAP - prior);
            take = (c < avail) ? c : avail;
        }
        lbase[j] = base;
        lcap[j]  = take;
        lhist[j] = 0u;                 // reuse as running local offset
    }
    __syncthreads();

#pragma unroll
    for (int k = 0; k < 16; ++k) {
        float2 xy = pxy[k];
        unsigned b = bucket_of(xy);
        unsigned idx = cbase + tid + (unsigned)k * 256u;
        unsigned loff = atomicAdd(&lhist[b], 1u);
        if (loff < lcap[b]) {
            unsigned pos = lbase[b] + loff;
            xybuf[pos] = xy;
            idxbuf[pos] = idx;
        } else {
            unsigned o = atomicAdd(ovf_cnt, 1u);
            if (o < OVF_CAP) { ovf_xy[o] = xy; ovf_idx[o] = idx; }
        }
    }
}

// ---- Pass 2: encode. 512 threads = 8 waves = 8 buckets per block.
// Grid 512 -> 4 blocks/CU x 8 waves = 32 waves/CU (100% occupancy).
// Levels 0-3 staged in LDS: offloads 25% of gather line-work from the TA
// pipe to the LDS pipe (round-4-vs-5 A/B showed this is worth ~15us). ----
__global__ __launch_bounds__(512) void encode_kernel(
    const float2* __restrict__ xybuf,
    const unsigned* __restrict__ idxbuf,
    const unsigned* __restrict__ cursor,
    const float2* __restrict__ tab,
    vfloat4* __restrict__ out)
{
    __shared__ float2 lds[NSTAGE];
    unsigned tid = threadIdx.x;

#define STAGE(L, W, B)                                                  \
    for (unsigned i = tid; i < (unsigned)((W)*(W)); i += 512u) {        \
        unsigned vy = i / (unsigned)(W), vx = i % (unsigned)(W);        \
        unsigned h = ((vx ^ (vy * PRIME)) & MASK) | ((unsigned)(L) << 19); \
        lds[(B) + i] = tab[h];                                          \
    }
    STAGE(0, W0, B0)
    STAGE(1, W1, B1)
    STAGE(2, W2, B2)
    STAGE(3, W3, B3)
#undef STAGE
    __syncthreads();

    unsigned wave = tid >> 6;              // 0..7: bucket within block
    unsigned lane = tid & 63u;
    unsigned lq   = lane & 3u;             // level quad: levels 4lq..4lq+3
    unsigned s0   = lane >> 2;             // 0..15: slot within iteration
    unsigned b    = blockIdx.x * 8u + wave;
    unsigned total = cursor[b] - b * CAP;
    unsigned cnt  = (total < CAP) ? total : CAP;
    unsigned l0   = lq << 2;
    unsigned pbase = b * CAP;

    const unsigned Wk[4] = { W0, W1, W2, W3 };
    const unsigned Bk[4] = { B0, B1, B2, B3 };

    for (unsigned s = s0; s < cnt; s += 16u) {
        float2 xy   = xybuf[pbase + s];
        unsigned idx = idxbuf[pbase + s];
        vfloat4 r[2];

        if (lq == 0u) {
            // levels 0-3 from LDS
#pragma unroll
            for (int k = 0; k < 4; ++k) {
                float sc = c_scale[k];
                float sx = xy.x * sc, sy = xy.y * sc;
                float fxf = floorf(sx), fyf = floorf(sy);
                float cxf = ceilf(sx),  cyf = ceilf(sy);
                float ox = sx - fxf, oy = sy - fyf;
                unsigned fx = (unsigned)(int)fxf, fy = (unsigned)(int)fyf;
                unsigned cx = (unsigned)(int)cxf, cy = (unsigned)(int)cyf;
                unsigned w = Wk[k], bb = Bk[k];
                float2 f0 = lds[bb + cy * w + cx];
                float2 f1 = lds[bb + fy * w + cx];
                float2 f2 = lds[bb + cy * w + fx];
                float2 f3 = lds[bb + fy * w + fx];
                float wox = 1.0f - ox, woy = 1.0f - oy;
                float f03x = f0.x * ox + f3.x * wox;
                float f03y = f0.y * ox + f3.y * wox;
                float f12x = f1.x * ox + f2.x * wox;
                float f12y = f1.y * ox + f2.y * wox;
                float ex = f03x * oy + f12x * woy;
                float ey = f03y * oy + f12y * woy;
                if ((k & 1) == 0) { r[k >> 1].x = ex; r[k >> 1].y = ey; }
                else              { r[k >> 1].z = ex; r[k >> 1].w = ey; }
            }
        } else {
            // levels 4lq..4lq+3 from global
#pragma unroll
            for (int k = 0; k < 4; ++k) {
                float ex, ey;
                enc_level(xy, l0 + (unsigned)k, tab, ex, ey);
                if ((k & 1) == 0) { r[k >> 1].x = ex; r[k >> 1].y = ey; }
                else              { r[k >> 1].z = ex; r[k >> 1].w = ey; }
            }
        }

        // 4 lq-threads of one point cover idx*8..idx*8+7: one aligned,
        // fully-written 128B record (2 lines) -> no write amplification.
        unsigned o = idx * 8u + lq * 2u;
        __builtin_nontemporal_store(r[0], &out[o]);
        __builtin_nontemporal_store(r[1], &out[o + 1]);
    }
}

// ---- Pass 3: encode overflow points directly (expected ~0-100 points) ----
__global__ __launch_bounds__(256) void fixup_kernel(
    const unsigned* __restrict__ ovf_cnt,
    const float2* __restrict__ ovf_xy,
    const unsigned* __restrict__ ovf_idx,
    const float2* __restrict__ tab,
    vfloat4* __restrict__ out)
{
    unsigned n = *ovf_cnt; if (n > OVF_CAP) n = OVF_CAP;
    unsigned stride = gridDim.x * 256u;
    for (unsigned p = blockIdx.x * 256u + threadIdx.x; p < n; p += stride) {
        float2 xy = ovf_xy[p];
        unsigned idx = ovf_idx[p];
        vfloat4 acc[8];
#pragma unroll
        for (int l = 0; l < 16; ++l) {
            float ex, ey;
            enc_level(xy, (unsigned)l, tab, ex, ey);
            if ((l & 1) == 0) { acc[l >> 1].x = ex; acc[l >> 1].y = ey; }
            else              { acc[l >> 1].z = ex; acc[l >> 1].w = ey; }
        }
#pragma unroll
        for (int q = 0; q < 8; ++q) out[idx * 8u + (unsigned)q] = acc[q];
    }
}

// ---- Fallback: proven round-0 unsorted kernel (ws too small; never expected) ----
__global__ __launch_bounds__(256) void hashenc_kernel(
    const float2* __restrict__ x,
    const float2* __restrict__ tab,
    vfloat4* __restrict__ out,
    unsigned pts_per_block)
{
    __shared__ float2 lds[NSTAGE];
    unsigned tid = threadIdx.x;

#define STAGE(L, W, B)                                                  \
    for (unsigned i = tid; i < (unsigned)((W)*(W)); i += 256u) {        \
        unsigned vy = i / (unsigned)(W), vx = i % (unsigned)(W);        \
        unsigned h = ((vx ^ (vy * PRIME)) & MASK) | ((unsigned)(L) << 19); \
        lds[(B) + i] = tab[h];                                          \
    }
    STAGE(0, W0, B0)
    STAGE(1, W1, B1)
    STAGE(2, W2, B2)
    STAGE(3, W3, B3)
#undef STAGE
    __syncthreads();

    const unsigned lq = tid & 3u;
    const unsigned lane_p = tid >> 2;
    const unsigned l0 = lq << 2;
    const unsigned bs = blockIdx.x * pts_per_block;
    unsigned be = bs + pts_per_block;
    if (be > NPTS) be = NPTS;

    const unsigned Wk[4] = { W0, W1, W2, W3 };
    const unsigned Bk[4] = { B0, B1, B2, B3 };

    for (unsigned p = bs + lane_p; p < be; p += 64u) {
        float2 xy = x[p];
        vfloat4 r[2];

        if (lq == 0u) {
#pragma unroll
            for (int k = 0; k < 4; ++k) {
                float s = c_scale[k];
                float sx = xy.x * s, sy = xy.y * s;
                float fxf = floorf(sx), fyf = floorf(sy);
                float cxf = ceilf(sx),  cyf = ceilf(sy);
                float ox = sx - fxf, oy = sy - fyf;
                unsigned fx = (unsigned)(int)fxf, fy = (unsigned)(int)fyf;
                unsigned cx = (unsigned)(int)cxf, cy = (unsigned)(int)cyf;
                unsigned w = Wk[k], b = Bk[k];
                float2 f0 = lds[b + cy * w + cx];
                float2 f1 = lds[b + fy * w + cx];
                float2 f2 = lds[b + cy * w + fx];
                float2 f3 = lds[b + fy * w + fx];
                float wox = 1.0f - ox, woy = 1.0f - oy;
                float f03x = f0.x * ox + f3.x * wox;
                float f03y = f0.y * ox + f3.y * wox;
                float f12x = f1.x * ox + f2.x * wox;
                float f12y = f1.y * ox + f2.y * wox;
                float ex = f03x * oy + f12x * woy;
                float ey = f03y * oy + f12y * woy;
                if ((k & 1) == 0) { r[k >> 1].x = ex; r[k >> 1].y = ey; }
                else              { r[k >> 1].z = ex; r[k >> 1].w = ey; }
            }
        } else {
#pragma unroll
            for (int k = 0; k < 4; ++k) {
                float ex, ey;
                enc_level(xy, l0 + (unsigned)k, tab, ex, ey);
                if ((k & 1) == 0) { r[k >> 1].x = ex; r[k >> 1].y = ey; }
                else              { r[k >> 1].z = ex; r[k >> 1].w = ey; }
            }
        }

        unsigned o = p * 8u + lq * 2u;
        __builtin_nontemporal_store(r[0], &out[o]);
        __builtin_nontemporal_store(r[1], &out[o + 1]);
    }
}

extern "C" void kernel_launch(void* const* d_in, const int* in_sizes, int n_in,
                              void* d_out, int out_size, void* d_ws, size_t ws_size,
                              hipStream_t stream)
{
    const float2* x   = (const float2*)d_in[0];
    const float2* tab = (const float2*)d_in[1];
    vfloat4* out = (vfloat4*)d_out;

    if (d_ws != nullptr && ws_size >= (size_t)WS_NEED) {
        char* ws = (char*)d_ws;
        unsigned* cursor  = (unsigned*)(ws + WS_CURSOR);
        unsigned* ovf_cnt = (unsigned*)(ws + WS_OVFCNT);
        float2*   ovf_xy  = (float2*)  (ws + WS_OVF_XY);
        unsigned* ovf_idx = (unsigned*)(ws + WS_OVF_IDX);
        float2*   xybuf   = (float2*)  (ws + WS_XYBUF);
        unsigned* idxbuf  = (unsigned*)(ws + WS_IDXBUF);

        init_kernel<<<16, 256, 0, stream>>>(cursor, ovf_cnt);
        sort_kernel<<<256, 256, 0, stream>>>(x, cursor, ovf_cnt, ovf_xy,
                                             ovf_idx, xybuf, idxbuf);
        encode_kernel<<<NBUK / 8, 512, 0, stream>>>(xybuf, idxbuf, cursor, tab, out);
        fixup_kernel<<<8, 256, 0, stream>>>(ovf_cnt, ovf_xy, ovf_idx, tab, out);
    } else {
        const unsigned n_blocks = 1536u;
        const unsigned ppb = (NPTS + n_blocks - 1u) / n_blocks;
        hashenc_kernel<<<n_blocks, 256, 0, stream>>>(x, tab, out, ppb);
    }
}